// Round 7
// baseline (50.858 us; speedup 1.0000x reference)
//
#include <hip/hip_runtime.h>
#include <hip/hip_bf16.h>
#if !__has_builtin(__builtin_amdgcn_cvt_pk_fp8_f32)
#include <hip/hip_fp8.h>
#endif

#define NS 2048          // speakers (= cols)
#define MU 16            // utterances
#define DD 256           // dim (= K)
#define NMROWS (NS*MU)   // 32768 rows
#define STRIPS 8
#define SC 256           // cols per strip (whole strip resident in LDS)
#define NSTEP 4          // 64-col steps per strip
#define BMROWS 256       // rows per main block (8 waves x 32 rows)
#define THR 8.0f

typedef float  f32x4  __attribute__((ext_vector_type(4)));
typedef float  f32x16 __attribute__((ext_vector_type(16)));
typedef int    i32x4  __attribute__((ext_vector_type(4)));

#define LOG2E 1.44269504088896340736f
#define LN2   0.69314718055994530942f

#if __has_builtin(__builtin_amdgcn_exp2f)
#define EXP2F(x) __builtin_amdgcn_exp2f(x)
#else
#define EXP2F(x) exp2f(x)
#endif
#if __has_builtin(__builtin_amdgcn_logf)
#define LOG2F(x) __builtin_amdgcn_logf(x)   // v_log_f32 = log2
#else
#define LOG2F(x) __log2f(x)
#endif

// pack 4 f32 -> 4 fp8 e4m3 (RNE) in one dword
__device__ __forceinline__ int pk4(float a, float b, float c, float d){
#if __has_builtin(__builtin_amdgcn_cvt_pk_fp8_f32)
  int v = __builtin_amdgcn_cvt_pk_fp8_f32(a, b, 0, false);
  v = __builtin_amdgcn_cvt_pk_fp8_f32(c, d, v, true);
  return v;
#else
  unsigned r = (unsigned)__hip_fp8_e4m3(a).__x
             | ((unsigned)__hip_fp8_e4m3(b).__x << 8)
             | ((unsigned)__hip_fp8_e4m3(c).__x << 16)
             | ((unsigned)__hip_fp8_e4m3(d).__x << 24);
  return (int)r;
#endif
}
__device__ __forceinline__ long mk64(int lo, int hi){
  return (long)(((unsigned long long)(unsigned)lo) |
                ((unsigned long long)(unsigned)hi << 32));
}

// centk8 layout (8B units): G(st,cg,hi,c32) = ((st*64 + cg)*2 + hi)*32 + c32
//   st = 16-elem k-chunk (0..15), cg = col>>5, c32 = col&31, hi = 8-k half.
// Within one st, a strip's 8 col-groups are 4 KiB contiguous -> lane-linear
// global_load_lds yields an LDS image whose wave b64 reads are 512B dense.

// ---- fused prep: fp8 scaled centroids (swizzled), fp8 embeddings (k16-major),
// ---- exact-fp32 excluded-self diagonal; emb read ONCE ----
__launch_bounds__(256)
__global__ void prep_kernel(const float* __restrict__ emb,
                            const float* __restrict__ wp,
                            long* __restrict__ centk8,
                            unsigned char* __restrict__ embk8,   // may be null
                            float* __restrict__ diag2){
  __shared__ float E[16*260];    // 16 rows x 256 dims, pad stride 260
  __shared__ float sm[256];
  const int t = threadIdx.x;
  const int n = blockIdx.x;      // speaker
  const float* src = emb + (size_t)n*MU*DD;

  #pragma unroll
  for (int i=0;i<4;i++){
    int g = i*1024 + t*4;                 // coalesced f32x4
    f32x4 v = *(const f32x4*)(src + g);
    int m = g >> 8, d = g & 255;
    *(f32x4*)&E[m*260 + d] = v;
  }
  __syncthreads();

  {
    float s = 0.f;
    #pragma unroll
    for (int m=0;m<16;m++) s += E[m*260 + t];
    sm[t] = s;
  }
  __syncthreads();

  const float w2 = wp[0] * LOG2E;

  if (t < 16){                            // scaled centroid, fp8, swizzled
    const float c16 = w2 * (1.0f/16.0f);
    const int st = t;
    const float* p = &sm[st*16];
    int q0 = pk4(p[0]*c16,  p[1]*c16,  p[2]*c16,  p[3]*c16);
    int q1 = pk4(p[4]*c16,  p[5]*c16,  p[6]*c16,  p[7]*c16);
    int q2 = pk4(p[8]*c16,  p[9]*c16,  p[10]*c16, p[11]*c16);
    int q3 = pk4(p[12]*c16, p[13]*c16, p[14]*c16, p[15]*c16);
    size_t base = ((size_t)(st*64 + (n>>5))*2)*32 + (n&31);
    centk8[base]      = mk64(q0, q1);     // hi=0 plane (k 0-7)
    centk8[base + 32] = mk64(q2, q3);     // hi=1 plane (k 8-15)
  }

  if (embk8){                             // fp8 embeddings, [st][row][16]
    int st = t >> 4, r = t & 15;
    const float* p = &E[r*260 + st*16];
    i32x4 o;
    #pragma unroll
    for (int q=0;q<4;q++){
      f32x4 v = *(const f32x4*)(p + q*4);
      o[q] = pk4(v[0], v[1], v[2], v[3]);
    }
    *(i32x4*)(embk8 + ((size_t)st*NMROWS + n*16 + r)*16) = o;
  }

  {                                       // excluded-self diagonal (exact fp32)
    int m = t >> 4, j = t & 15;
    float acc = 0.f;
    #pragma unroll
    for (int i=0;i<16;i++){
      int d = j + 16*i;
      float e = E[m*260 + d];
      acc += e * (sm[d] - e);
    }
    acc += __shfl_xor(acc, 1, 16);
    acc += __shfl_xor(acc, 2, 16);
    acc += __shfl_xor(acc, 4, 16);
    acc += __shfl_xor(acc, 8, 16);
    if (j==0) diag2[n*16 + m] = acc * (w2 * (1.0f/15.0f));
  }
}

// ---- stage whole 256-col strip (64 KiB) via async global->LDS DMA ----
// 8 waves x 8 rounds x (64 lanes x 16B) = 64 KiB; per st, strip = 4 KiB dense
__device__ __forceinline__ void stage_strip(const long* __restrict__ centk8,
                                            long* lds, int cg0,
                                            int wave, int lane){
  #pragma unroll
  for (int i=0;i<8;i++){
    const int L  = wave*8 + i;    // 0..63
    const int st = L >> 2;        // k16-chunk
    const int q  = L & 3;         // quarter of the 4 KiB st-chunk
    const long* g = centk8 + (size_t)(st*64 + cg0)*64 + q*128 + lane*2;
    __builtin_amdgcn_global_load_lds(
        (const __attribute__((address_space(1))) void*)g,
        (__attribute__((address_space(3))) void*)(lds + (size_t)st*512 + q*128),
        16, 0, 0);
  }
}

#define MFMA8(a,b,c) __builtin_amdgcn_mfma_f32_32x32x16_fp8_fp8(a,b,c,0,0,0)

// ---- main: fp8 A in regs (1 row/lane), whole strip in LDS, ONE barrier ----
template<bool FROMF32>
__launch_bounds__(512,4)
__global__ void ge2e_main(const float* __restrict__ embf,
                          const unsigned char* __restrict__ embk8,
                          const long* __restrict__ centk8,
                          const float* __restrict__ diag2,
                          float2* __restrict__ msbuf){
  __shared__ long Bs[8192];   // 64 KiB: the whole strip, staged once

  const int tid  = threadIdx.x;
  const int lane = tid & 63;
  const int wave = tid >> 6;
  const int l31  = lane & 31, hi = lane >> 5;
  const int strip  = blockIdx.x & 7;
  const int rowBlk = blockIdx.x >> 3;
  const int c0 = strip * SC;
  const int rowA = rowBlk*BMROWS + wave*32 + l31;   // this lane's (only) row

  stage_strip(centk8, Bs, c0 >> 5, wave, lane);

  long af[16];
  if constexpr (FROMF32){
    const float* rp = embf + (size_t)rowA*DD;
    #pragma unroll
    for (int st=0; st<16; ++st){
      f32x4 v0 = *(const f32x4*)(rp + 16*st + 8*hi);
      f32x4 v1 = *(const f32x4*)(rp + 16*st + 8*hi + 4);
      af[st] = mk64(pk4(v0[0],v0[1],v0[2],v0[3]), pk4(v1[0],v1[1],v1[2],v1[3]));
    }
  } else {
    #pragma unroll
    for (int st=0; st<16; ++st)
      af[st] = *(const long*)(embk8 + ((size_t)st*NMROWS + rowA)*16 + hi*8);
  }

  const float dv  = diag2[rowA];
  const int   lab = rowA >> 4;
  const int   labc0 = rowBlk*16;                     // 16 label-cols of block
  const bool  hasdiag = (labc0 >= c0) && (labc0 < c0 + SC);
  const int   dstep = (labc0 - c0) >> 6;             // valid only if hasdiag
  const int   dgrp  = ((labc0 - c0) >> 5) & 1;

  float mneg = 0.f, s = 0.f;    // mneg = -running_max (log2 domain)

  __syncthreads();   // the ONLY barrier: strip staged, af landed

  #pragma unroll
  for (int step=0; step<NSTEP; ++step){
    f32x16 ci;
    #pragma unroll
    for (int i=0;i<16;i++) ci[i] = mneg;   // C-init folds the max subtract

    f32x16 accA, accB;
    {
      const long bA = Bs[(size_t)((0*8 + step*2    )*2 + hi)*32 + l31];
      const long bB = Bs[(size_t)((0*8 + step*2 + 1)*2 + hi)*32 + l31];
      accA = MFMA8(bA, af[0], ci);
      accB = MFMA8(bB, af[0], ci);
    }
    #pragma unroll
    for (int st=1; st<16; ++st){           // two independent chains (2x ILP)
      const long bA = Bs[(size_t)((st*8 + step*2    )*2 + hi)*32 + l31];
      const long bB = Bs[(size_t)((st*8 + step*2 + 1)*2 + hi)*32 + l31];
      accA = MFMA8(bA, af[st], accA);
      accB = MFMA8(bB, af[st], accB);
    }

    if (hasdiag && step == dstep){         // block-uniform, one step, one group
      int colbase = c0 + step*64 + dgrp*32 + 4*hi;
      if (dgrp == 0){
        #pragma unroll
        for (int r=0;r<16;r++){
          int col = colbase + (r&3) + 8*(r>>2);
          if (col == lab) accA[r] = dv + mneg;   // exact-fp32 self term
        }
      } else {
        #pragma unroll
        for (int r=0;r<16;r++){
          int col = colbase + (r&3) + 8*(r>>2);
          if (col == lab) accB[r] = dv + mneg;
        }
      }
    }

    // acc = logit - m. Online softmax, lane-local, defer-max (THR=8)
    float xa0 = fmaxf(fmaxf(fmaxf(accA[0],accA[1]),fmaxf(accA[2],accA[3])),
                      fmaxf(fmaxf(accA[4],accA[5]),fmaxf(accA[6],accA[7])));
    float xa1 = fmaxf(fmaxf(fmaxf(accA[8],accA[9]),fmaxf(accA[10],accA[11])),
                      fmaxf(fmaxf(accA[12],accA[13]),fmaxf(accA[14],accA[15])));
    float xb0 = fmaxf(fmaxf(fmaxf(accB[0],accB[1]),fmaxf(accB[2],accB[3])),
                      fmaxf(fmaxf(accB[4],accB[5]),fmaxf(accB[6],accB[7])));
    float xb1 = fmaxf(fmaxf(fmaxf(accB[8],accB[9]),fmaxf(accB[10],accB[11])),
                      fmaxf(fmaxf(accB[12],accB[13]),fmaxf(accB[14],accB[15])));
    float tm = fmaxf(fmaxf(xa0,xa1), fmaxf(xb0,xb1));

    if (__any(tm > THR)){                  // triggers on early steps only
      float d = fmaxf(tm, 0.f);
      s *= EXP2F(-d);
      mneg -= d;
      float a0=0.f, b0=0.f;
      #pragma unroll
      for (int r=0;r<16;r++){ a0 += EXP2F(accA[r]-d); b0 += EXP2F(accB[r]-d); }
      s += a0 + b0;
    } else {                               // fast path: exp2 directly
      float a0 = EXP2F(accA[0])+EXP2F(accA[1])+EXP2F(accA[2])+EXP2F(accA[3]);
      float a1 = EXP2F(accA[4])+EXP2F(accA[5])+EXP2F(accA[6])+EXP2F(accA[7]);
      float a2 = EXP2F(accA[8])+EXP2F(accA[9])+EXP2F(accA[10])+EXP2F(accA[11]);
      float a3 = EXP2F(accA[12])+EXP2F(accA[13])+EXP2F(accA[14])+EXP2F(accA[15]);
      float b0 = EXP2F(accB[0])+EXP2F(accB[1])+EXP2F(accB[2])+EXP2F(accB[3]);
      float b1 = EXP2F(accB[4])+EXP2F(accB[5])+EXP2F(accB[6])+EXP2F(accB[7]);
      float b2 = EXP2F(accB[8])+EXP2F(accB[9])+EXP2F(accB[10])+EXP2F(accB[11]);
      float b3 = EXP2F(accB[12])+EXP2F(accB[13])+EXP2F(accB[14])+EXP2F(accB[15]);
      s += ((a0+a1)+(a2+a3)) + ((b0+b1)+(b2+b3));
    }
  }

  // merge hi-halves (same row, disjoint col subsets)
  float m  = -mneg;
  float mo = __shfl_xor(m,32,64), so = __shfl_xor(s,32,64);
  float mm = fmaxf(m,mo);
  float ss = s*EXP2F(m-mm) + so*EXP2F(mo-mm);

  if (hi==0) msbuf[(size_t)strip*NMROWS + rowA] = make_float2(mm, ss);
}

// ---- merge 8 strips per row -> per-row loss term -> per-block partial ----
__launch_bounds__(512)
__global__ void merge_kernel(const float2* __restrict__ msbuf,
                             const float* __restrict__ diag2,
                             float* __restrict__ partials){
  __shared__ float sh[8];
  const int row = blockIdx.x*512 + threadIdx.x;
  float2 p[STRIPS];
  #pragma unroll
  for (int k=0;k<STRIPS;k++) p[k] = msbuf[(size_t)k*NMROWS + row];
  float mm = p[0].x;
  #pragma unroll
  for (int k=1;k<STRIPS;k++) mm = fmaxf(mm, p[k].x);
  float ss = 0.f;
  #pragma unroll
  for (int k=0;k<STRIPS;k++) ss += p[k].y * EXP2F(p[k].x - mm);
  float term = LN2*(mm + LOG2F(ss) - diag2[row]);
  #pragma unroll
  for (int off=32; off; off>>=1) term += __shfl_xor(term, off, 64);
  if ((threadIdx.x & 63)==0) sh[threadIdx.x>>6] = term;
  __syncthreads();
  if (threadIdx.x==0){
    float v = 0.f;
    #pragma unroll
    for (int i=0;i<8;i++) v += sh[i];
    partials[blockIdx.x] = v;
  }
}

__global__ void final_kernel(const float* __restrict__ partials,
                             float* __restrict__ out){
  int tid = threadIdx.x;              // 64
  float v = partials[tid];
  #pragma unroll
  for (int off=32; off; off>>=1) v += __shfl_xor(v, off, 64);
  if (tid==0) out[0] = v * (1.0f/NMROWS);
}

extern "C" void kernel_launch(void* const* d_in, const int* in_sizes, int n_in,
                              void* d_out, int out_size, void* d_ws, size_t ws_size,
                              hipStream_t stream){
  const float* emb = (const float*)d_in[0];
  const float* wp  = (const float*)d_in[1];
  // d_in[2] (b) cancels in the loss; unused.
  float* out = (float*)d_out;
  char* ws = (char*)d_ws;

  const size_t centk_b = (size_t)NS*DD;            // 512 KiB (fp8)
  const size_t embk_b  = (size_t)NMROWS*DD;        // 8 MiB  (fp8)
  const size_t diag_b  = (size_t)NMROWS*4;         // 128 KiB
  const size_t ms_b    = (size_t)STRIPS*NMROWS*8;  // 2 MiB
  const bool useEmbk = ws_size >= centk_b + embk_b + diag_b + ms_b + 1024;

  long* centk8 = (long*)ws;
  size_t off = centk_b;
  unsigned char* embk8 = useEmbk ? (unsigned char*)(ws + off) : nullptr;
  if (useEmbk) off += embk_b;
  float*  diag2 = (float*)(ws + off);  off += diag_b;
  float2* msbuf = (float2*)(ws + off); off += ms_b;
  float*  parts = (float*)(ws + off);

  prep_kernel<<<NS, 256, 0, stream>>>(emb, wp, centk8, embk8, diag2);
  if (useEmbk)
    ge2e_main<false><<<(NMROWS/BMROWS)*STRIPS, 512, 0, stream>>>(emb, embk8, centk8, diag2, msbuf);
  else
    ge2e_main<true><<<(NMROWS/BMROWS)*STRIPS, 512, 0, stream>>>(emb, embk8, centk8, diag2, msbuf);
  merge_kernel<<<NMROWS/512, 512, 0, stream>>>(msbuf, diag2, parts);
  final_kernel<<<1, 64, 0, stream>>>(parts, out);
}

// Round 8
// 41.612 us; speedup vs baseline: 1.2222x; 1.2222x over previous
//
#include <hip/hip_runtime.h>
#include <hip/hip_bf16.h>
#if !__has_builtin(__builtin_amdgcn_cvt_pk_fp8_f32)
#include <hip/hip_fp8.h>
#endif

#define NS 2048          // speakers (= cols)
#define MU 16            // utterances
#define DD 256           // dim (= K)
#define NMROWS (NS*MU)   // 32768 rows
#define STRIPS 8
#define SC 256           // cols per strip
#define NSTEP 4          // 64-col steps per strip
#define BMROWS 128       // rows per main block (4 waves x 32 rows)
#define THR 8.0f

typedef float  f32x4  __attribute__((ext_vector_type(4)));
typedef float  f32x16 __attribute__((ext_vector_type(16)));
typedef int    i32x4  __attribute__((ext_vector_type(4)));
typedef int    i32x8  __attribute__((ext_vector_type(8)));

#define LOG2E 1.44269504088896340736f
#define LN2   0.69314718055994530942f

#if __has_builtin(__builtin_amdgcn_exp2f)
#define EXP2F(x) __builtin_amdgcn_exp2f(x)
#else
#define EXP2F(x) exp2f(x)
#endif
#if __has_builtin(__builtin_amdgcn_logf)
#define LOG2F(x) __builtin_amdgcn_logf(x)   // v_log_f32 = log2
#else
#define LOG2F(x) __log2f(x)
#endif

// pack 4 f32 -> 4 fp8 e4m3 (RNE) in one dword (byte0 = first arg)
__device__ __forceinline__ int pk4(float a, float b, float c, float d){
#if __has_builtin(__builtin_amdgcn_cvt_pk_fp8_f32)
  int v = __builtin_amdgcn_cvt_pk_fp8_f32(a, b, 0, false);
  v = __builtin_amdgcn_cvt_pk_fp8_f32(c, d, v, true);
  return v;
#else
  unsigned r = (unsigned)__hip_fp8_e4m3(a).__x
             | ((unsigned)__hip_fp8_e4m3(b).__x << 8)
             | ((unsigned)__hip_fp8_e4m3(c).__x << 16)
             | ((unsigned)__hip_fp8_e4m3(d).__x << 24);
  return (int)r;
#endif
}

// centk16 layout: [st][col] 16B units (st = 16-elem k-chunk, k = st*16 + j).
// embk8  layout: [st][row] 16B units, same j order -> A/B byte->k maps match.

// ---- fused prep: fp8 scaled centroids, fp8 embeddings, exact-fp32 diag ----
__launch_bounds__(256)
__global__ void prep_kernel(const float* __restrict__ emb,
                            const float* __restrict__ wp,
                            i32x4* __restrict__ centk16,
                            unsigned char* __restrict__ embk8,   // may be null
                            float* __restrict__ diag2){
  __shared__ float E[16*260];    // 16 rows x 256 dims, pad stride 260
  __shared__ float sm[256];
  const int t = threadIdx.x;
  const int n = blockIdx.x;      // speaker
  const float* src = emb + (size_t)n*MU*DD;

  #pragma unroll
  for (int i=0;i<4;i++){
    int g = i*1024 + t*4;                 // coalesced f32x4
    f32x4 v = *(const f32x4*)(src + g);
    int m = g >> 8, d = g & 255;
    *(f32x4*)&E[m*260 + d] = v;
  }
  __syncthreads();

  {
    float s = 0.f;
    #pragma unroll
    for (int m=0;m<16;m++) s += E[m*260 + t];
    sm[t] = s;
  }
  __syncthreads();

  const float w2 = wp[0] * LOG2E;

  if (t < 16){                            // scaled centroid, fp8, [st][col]
    const float c16 = w2 * (1.0f/16.0f);
    const int st = t;
    const float* p = &sm[st*16];
    i32x4 o;
    #pragma unroll
    for (int q=0;q<4;q++)
      o[q] = pk4(p[q*4]*c16, p[q*4+1]*c16, p[q*4+2]*c16, p[q*4+3]*c16);
    centk16[(size_t)st*NS + n] = o;
  }

  if (embk8){                             // fp8 embeddings, [st][row][16]
    int st = t >> 4, r = t & 15;
    const float* p = &E[r*260 + st*16];
    i32x4 o;
    #pragma unroll
    for (int q=0;q<4;q++){
      f32x4 v = *(const f32x4*)(p + q*4);
      o[q] = pk4(v[0], v[1], v[2], v[3]);
    }
    *(i32x4*)(embk8 + ((size_t)st*NMROWS + n*16 + r)*16) = o;
  }

  {                                       // excluded-self diagonal (exact fp32)
    int m = t >> 4, j = t & 15;
    float acc = 0.f;
    #pragma unroll
    for (int i=0;i<16;i++){
      int d = j + 16*i;
      float e = E[m*260 + d];
      acc += e * (sm[d] - e);
    }
    acc += __shfl_xor(acc, 1, 16);
    acc += __shfl_xor(acc, 2, 16);
    acc += __shfl_xor(acc, 4, 16);
    acc += __shfl_xor(acc, 8, 16);
    if (j==0) diag2[n*16 + m] = acc * (w2 * (1.0f/15.0f));
  }
}

// ---- stage one 64-col fp8 B step-tile (16 KiB) via async global->LDS DMA ----
// LDS image (16B units): idx = st*64 + colLocal; per st the 64 cols are 1 KiB
// dense in global ([st][col] layout) -> lane-linear DMA, coalesced.
__device__ __forceinline__ void stage_b(const i32x4* __restrict__ centk16,
                                        i32x4* lds, int col0,
                                        int wave, int lane){
  #pragma unroll
  for (int i=0;i<4;i++){
    const int st = i*4 + wave;
    const i32x4* g = centk16 + (size_t)st*NS + col0 + lane;
    __builtin_amdgcn_global_load_lds(
        (const __attribute__((address_space(1))) void*)g,
        (__attribute__((address_space(3))) void*)(lds + (size_t)st*64),
        16, 0, 0);
  }
}

// MX-scaled fp8 MFMA, K=64, identity E8M0 scales (0x7F -> 2^0)
#define MFMAS(a,b,c) __builtin_amdgcn_mfma_scale_f32_32x32x64_f8f6f4( \
    a, b, c, 0, 0, 0, 0x7f7f7f7fu, 0, 0x7f7f7f7fu)

// ---- main: fp8 A in regs (1 row/lane), 64-col steps, 2 indep K=64 chains ----
template<bool FROMF32>
__launch_bounds__(256,4)
__global__ void ge2e_main(const float* __restrict__ embf,
                          const unsigned char* __restrict__ embk8,
                          const i32x4* __restrict__ centk16,
                          const float* __restrict__ diag2,
                          float2* __restrict__ msbuf){
  __shared__ i32x4 Bbuf[2][1024];   // 2 x 16 KiB

  const int tid  = threadIdx.x;
  const int lane = tid & 63;
  const int wave = tid >> 6;
  const int l31  = lane & 31, hi = lane >> 5;
  const int strip  = blockIdx.x & 7;
  const int rowBlk = blockIdx.x >> 3;
  const int c0 = strip * SC;
  const int rowA = rowBlk*BMROWS + wave*32 + l31;   // this lane's (only) row

  stage_b(centk16, &Bbuf[0][0], c0, wave, lane);    // step 0

  // A fragments: chunk c covers k = c*64 + hi*32 + (0..31) = st {4c+2hi, +1}
  i32x8 af[4];
  if constexpr (FROMF32){
    const float* rp = embf + (size_t)rowA*DD;
    #pragma unroll
    for (int c=0;c<4;c++){
      i32x8 o;
      #pragma unroll
      for (int h=0;h<2;h++){
        const float* q = rp + (4*c + 2*hi + h)*16;
        #pragma unroll
        for (int j=0;j<4;j++)
          o[h*4+j] = pk4(q[j*4], q[j*4+1], q[j*4+2], q[j*4+3]);
      }
      af[c] = o;
    }
  } else {
    #pragma unroll
    for (int c=0;c<4;c++){
      i32x4 x = *(const i32x4*)(embk8 + ((size_t)(4*c+2*hi  )*NMROWS + rowA)*16);
      i32x4 y = *(const i32x4*)(embk8 + ((size_t)(4*c+2*hi+1)*NMROWS + rowA)*16);
      i32x8 o; o[0]=x[0];o[1]=x[1];o[2]=x[2];o[3]=x[3];
               o[4]=y[0];o[5]=y[1];o[6]=y[2];o[7]=y[3];
      af[c] = o;
    }
  }

  const float dv  = diag2[rowA];
  const int   lab = rowA >> 4;
  const int   labc0 = rowBlk*8;                      // 8 label-cols of block
  const bool  hasdiag = (labc0 >= c0) && (labc0 < c0 + SC);
  const int   dstep = (labc0 - c0) >> 6;             // valid only if hasdiag
  const int   dgrp  = ((labc0 - c0) >> 5) & 1;

  float mneg = 0.f, s = 0.f;      // mneg = -running_max (log2 domain)

  __syncthreads();   // step-0 staging (all waves) drained

  for (int step=0; step<NSTEP; ++step){
    const int cb_ = step & 1;
    if (step+1 < NSTEP)
      stage_b(centk16, &Bbuf[cb_^1][0], c0 + (step+1)*64, wave, lane);

    const i32x4* cur = &Bbuf[cb_][0];

    f32x16 ci;
    #pragma unroll
    for (int i=0;i<16;i++) ci[i] = mneg;   // C-init folds the max subtract

    f32x16 accA = ci, accB = ci;
    #pragma unroll
    for (int c=0;c<4;c++){                 // two independent chains (2x ILP)
      i32x4 a0 = cur[(4*c+2*hi  )*64      + l31];
      i32x4 a1 = cur[(4*c+2*hi+1)*64      + l31];
      i32x4 b0 = cur[(4*c+2*hi  )*64 + 32 + l31];
      i32x4 b1 = cur[(4*c+2*hi+1)*64 + 32 + l31];
      i32x8 bA; bA[0]=a0[0];bA[1]=a0[1];bA[2]=a0[2];bA[3]=a0[3];
                bA[4]=a1[0];bA[5]=a1[1];bA[6]=a1[2];bA[7]=a1[3];
      i32x8 bB; bB[0]=b0[0];bB[1]=b0[1];bB[2]=b0[2];bB[3]=b0[3];
                bB[4]=b1[0];bB[5]=b1[1];bB[6]=b1[2];bB[7]=b1[3];
      accA = MFMAS(bA, af[c], accA);
      accB = MFMAS(bB, af[c], accB);
    }

    if (hasdiag && step == dstep){         // block-uniform, one step, one group
      int colbase = c0 + step*64 + dgrp*32 + 4*hi;
      if (dgrp == 0){
        #pragma unroll
        for (int r=0;r<16;r++){
          int col = colbase + (r&3) + 8*(r>>2);
          if (col == lab) accA[r] = dv + mneg;   // exact-fp32 self term
        }
      } else {
        #pragma unroll
        for (int r=0;r<16;r++){
          int col = colbase + (r&3) + 8*(r>>2);
          if (col == lab) accB[r] = dv + mneg;
        }
      }
    }

    // acc = logit - m. Online softmax, lane-local, defer-max (THR=8)
    float xa0 = fmaxf(fmaxf(fmaxf(accA[0],accA[1]),fmaxf(accA[2],accA[3])),
                      fmaxf(fmaxf(accA[4],accA[5]),fmaxf(accA[6],accA[7])));
    float xa1 = fmaxf(fmaxf(fmaxf(accA[8],accA[9]),fmaxf(accA[10],accA[11])),
                      fmaxf(fmaxf(accA[12],accA[13]),fmaxf(accA[14],accA[15])));
    float xb0 = fmaxf(fmaxf(fmaxf(accB[0],accB[1]),fmaxf(accB[2],accB[3])),
                      fmaxf(fmaxf(accB[4],accB[5]),fmaxf(accB[6],accB[7])));
    float xb1 = fmaxf(fmaxf(fmaxf(accB[8],accB[9]),fmaxf(accB[10],accB[11])),
                      fmaxf(fmaxf(accB[12],accB[13]),fmaxf(accB[14],accB[15])));
    float tm = fmaxf(fmaxf(xa0,xa1), fmaxf(xb0,xb1));

    if (__any(tm > THR)){                  // triggers on early steps only
      float d = fmaxf(tm, 0.f);
      s *= EXP2F(-d);
      mneg -= d;
      float a0=0.f, b0=0.f;
      #pragma unroll
      for (int r=0;r<16;r++){ a0 += EXP2F(accA[r]-d); b0 += EXP2F(accB[r]-d); }
      s += a0 + b0;
    } else {                               // fast path: exp2 directly
      float a0 = EXP2F(accA[0])+EXP2F(accA[1])+EXP2F(accA[2])+EXP2F(accA[3]);
      float a1 = EXP2F(accA[4])+EXP2F(accA[5])+EXP2F(accA[6])+EXP2F(accA[7]);
      float a2 = EXP2F(accA[8])+EXP2F(accA[9])+EXP2F(accA[10])+EXP2F(accA[11]);
      float a3 = EXP2F(accA[12])+EXP2F(accA[13])+EXP2F(accA[14])+EXP2F(accA[15]);
      float b0 = EXP2F(accB[0])+EXP2F(accB[1])+EXP2F(accB[2])+EXP2F(accB[3]);
      float b1 = EXP2F(accB[4])+EXP2F(accB[5])+EXP2F(accB[6])+EXP2F(accB[7]);
      float b2 = EXP2F(accB[8])+EXP2F(accB[9])+EXP2F(accB[10])+EXP2F(accB[11]);
      float b3 = EXP2F(accB[12])+EXP2F(accB[13])+EXP2F(accB[14])+EXP2F(accB[15]);
      s += ((a0+a1)+(a2+a3)) + ((b0+b1)+(b2+b3));
    }

    asm volatile("s_waitcnt vmcnt(0)" ::: "memory");  // own prefetch landed
    __builtin_amdgcn_s_barrier();                     // all reads of cur done
  }

  // merge hi-halves (same row, disjoint col subsets)
  float m  = -mneg;
  float mo = __shfl_xor(m,32,64), so = __shfl_xor(s,32,64);
  float mm = fmaxf(m,mo);
  float ss = s*EXP2F(m-mm) + so*EXP2F(mo-mm);

  if (hi==0) msbuf[(size_t)strip*NMROWS + rowA] = make_float2(mm, ss);
}

// ---- merge 8 strips per row -> per-row loss term -> per-block partial ----
__launch_bounds__(512)
__global__ void merge_kernel(const float2* __restrict__ msbuf,
                             const float* __restrict__ diag2,
                             float* __restrict__ partials){
  __shared__ float sh[8];
  const int row = blockIdx.x*512 + threadIdx.x;
  float2 p[STRIPS];
  #pragma unroll
  for (int k=0;k<STRIPS;k++) p[k] = msbuf[(size_t)k*NMROWS + row];
  float mm = p[0].x;
  #pragma unroll
  for (int k=1;k<STRIPS;k++) mm = fmaxf(mm, p[k].x);
  float ss = 0.f;
  #pragma unroll
  for (int k=0;k<STRIPS;k++) ss += p[k].y * EXP2F(p[k].x - mm);
  float term = LN2*(mm + LOG2F(ss) - diag2[row]);
  #pragma unroll
  for (int off=32; off; off>>=1) term += __shfl_xor(term, off, 64);
  if ((threadIdx.x & 63)==0) sh[threadIdx.x>>6] = term;
  __syncthreads();
  if (threadIdx.x==0){
    float v = 0.f;
    #pragma unroll
    for (int i=0;i<8;i++) v += sh[i];
    partials[blockIdx.x] = v;
  }
}

__global__ void final_kernel(const float* __restrict__ partials,
                             float* __restrict__ out){
  int tid = threadIdx.x;              // 64
  float v = partials[tid];
  #pragma unroll
  for (int off=32; off; off>>=1) v += __shfl_xor(v, off, 64);
  if (tid==0) out[0] = v * (1.0f/NMROWS);
}

extern "C" void kernel_launch(void* const* d_in, const int* in_sizes, int n_in,
                              void* d_out, int out_size, void* d_ws, size_t ws_size,
                              hipStream_t stream){
  const float* emb = (const float*)d_in[0];
  const float* wp  = (const float*)d_in[1];
  // d_in[2] (b) cancels in the loss; unused.
  float* out = (float*)d_out;
  char* ws = (char*)d_ws;

  const size_t centk_b = (size_t)NS*DD;            // 512 KiB (fp8)
  const size_t embk_b  = (size_t)NMROWS*DD;        // 8 MiB  (fp8)
  const size_t diag_b  = (size_t)NMROWS*4;         // 128 KiB
  const size_t ms_b    = (size_t)STRIPS*NMROWS*8;  // 2 MiB
  const bool useEmbk = ws_size >= centk_b + embk_b + diag_b + ms_b + 1024;

  i32x4* centk16 = (i32x4*)ws;
  size_t off = centk_b;
  unsigned char* embk8 = useEmbk ? (unsigned char*)(ws + off) : nullptr;
  if (useEmbk) off += embk_b;
  float*  diag2 = (float*)(ws + off);  off += diag_b;
  float2* msbuf = (float2*)(ws + off); off += ms_b;
  float*  parts = (float*)(ws + off);

  prep_kernel<<<NS, 256, 0, stream>>>(emb, wp, centk16, embk8, diag2);
  if (useEmbk)
    ge2e_main<false><<<(NMROWS/BMROWS)*STRIPS, 256, 0, stream>>>(emb, embk8, centk16, diag2, msbuf);
  else
    ge2e_main<true><<<(NMROWS/BMROWS)*STRIPS, 256, 0, stream>>>(emb, embk8, centk16, diag2, msbuf);
  merge_kernel<<<NMROWS/512, 512, 0, stream>>>(msbuf, diag2, parts);
  final_kernel<<<1, 64, 0, stream>>>(parts, out);
}

// Round 9
// 41.386 us; speedup vs baseline: 1.2289x; 1.0054x over previous
//
#include <hip/hip_runtime.h>
#include <hip/hip_bf16.h>
#if !__has_builtin(__builtin_amdgcn_cvt_pk_fp8_f32)
#include <hip/hip_fp8.h>
#endif

#define NS 2048          // speakers (= cols)
#define MU 16            // utterances
#define DD 256           // dim (= K)
#define NMROWS (NS*MU)   // 32768 rows
#define STRIPS 8
#define SC 256           // cols per strip
#define NSTEP 4          // 64-col steps per strip
#define BMROWS 256       // rows per main block (4 waves x 32 rows x M_rep=2)
#define THR 8.0f

typedef float  f32x4  __attribute__((ext_vector_type(4)));
typedef float  f32x16 __attribute__((ext_vector_type(16)));
typedef int    i32x4  __attribute__((ext_vector_type(4)));
typedef int    i32x8  __attribute__((ext_vector_type(8)));

#define LOG2E 1.44269504088896340736f
#define LN2   0.69314718055994530942f

#if __has_builtin(__builtin_amdgcn_exp2f)
#define EXP2F(x) __builtin_amdgcn_exp2f(x)
#else
#define EXP2F(x) exp2f(x)
#endif
#if __has_builtin(__builtin_amdgcn_logf)
#define LOG2F(x) __builtin_amdgcn_logf(x)   // v_log_f32 = log2
#else
#define LOG2F(x) __log2f(x)
#endif

// pack 4 f32 -> 4 fp8 e4m3 (RNE) in one dword (byte0 = first arg)
__device__ __forceinline__ int pk4(float a, float b, float c, float d){
#if __has_builtin(__builtin_amdgcn_cvt_pk_fp8_f32)
  int v = __builtin_amdgcn_cvt_pk_fp8_f32(a, b, 0, false);
  v = __builtin_amdgcn_cvt_pk_fp8_f32(c, d, v, true);
  return v;
#else
  unsigned r = (unsigned)__hip_fp8_e4m3(a).__x
             | ((unsigned)__hip_fp8_e4m3(b).__x << 8)
             | ((unsigned)__hip_fp8_e4m3(c).__x << 16)
             | ((unsigned)__hip_fp8_e4m3(d).__x << 24);
  return (int)r;
#endif
}

// max of 16 floats, max3-friendly shape (clang fuses fmaxf pairs to v_max3)
__device__ __forceinline__ float max16(const f32x16& v){
  float t0 = fmaxf(fmaxf(v[0], v[1]), v[2]);
  float t1 = fmaxf(fmaxf(v[3], v[4]), v[5]);
  float t2 = fmaxf(fmaxf(v[6], v[7]), v[8]);
  float t3 = fmaxf(fmaxf(v[9], v[10]), v[11]);
  float t4 = fmaxf(fmaxf(v[12], v[13]), v[14]);
  return fmaxf(fmaxf(fmaxf(t0, t1), t2), fmaxf(fmaxf(t3, t4), v[15]));
}

// centk16 layout: [st][col] 16B units (st = 16-elem k-chunk, k = st*16 + j).
// embk8  layout: [st][row] 16B units, same j order -> A/B byte->k maps match.

// ---- fused prep: fp8 scaled centroids, fp8 embeddings, exact-fp32 diag ----
__launch_bounds__(256)
__global__ void prep_kernel(const float* __restrict__ emb,
                            const float* __restrict__ wp,
                            i32x4* __restrict__ centk16,
                            unsigned char* __restrict__ embk8,   // may be null
                            float* __restrict__ diag2){
  __shared__ float E[16*260];    // 16 rows x 256 dims, pad stride 260
  __shared__ float sm[256];
  const int t = threadIdx.x;
  const int n = blockIdx.x;      // speaker
  const float* src = emb + (size_t)n*MU*DD;

  #pragma unroll
  for (int i=0;i<4;i++){
    int g = i*1024 + t*4;                 // coalesced f32x4
    f32x4 v = *(const f32x4*)(src + g);
    int m = g >> 8, d = g & 255;
    *(f32x4*)&E[m*260 + d] = v;
  }
  __syncthreads();

  {
    float s = 0.f;
    #pragma unroll
    for (int m=0;m<16;m++) s += E[m*260 + t];
    sm[t] = s;
  }
  __syncthreads();

  const float w2 = wp[0] * LOG2E;

  if (t < 16){                            // scaled centroid, fp8, [st][col]
    const float c16 = w2 * (1.0f/16.0f);
    const int st = t;
    const float* p = &sm[st*16];
    i32x4 o;
    #pragma unroll
    for (int q=0;q<4;q++)
      o[q] = pk4(p[q*4]*c16, p[q*4+1]*c16, p[q*4+2]*c16, p[q*4+3]*c16);
    centk16[(size_t)st*NS + n] = o;
  }

  if (embk8){                             // fp8 embeddings, [st][row][16]
    int st = t >> 4, r = t & 15;
    const float* p = &E[r*260 + st*16];
    i32x4 o;
    #pragma unroll
    for (int q=0;q<4;q++){
      f32x4 v = *(const f32x4*)(p + q*4);
      o[q] = pk4(v[0], v[1], v[2], v[3]);
    }
    *(i32x4*)(embk8 + ((size_t)st*NMROWS + n*16 + r)*16) = o;
  }

  {                                       // excluded-self diagonal (exact fp32)
    int m = t >> 4, j = t & 15;
    float acc = 0.f;
    #pragma unroll
    for (int i=0;i<16;i++){
      int d = j + 16*i;
      float e = E[m*260 + d];
      acc += e * (sm[d] - e);
    }
    acc += __shfl_xor(acc, 1, 16);
    acc += __shfl_xor(acc, 2, 16);
    acc += __shfl_xor(acc, 4, 16);
    acc += __shfl_xor(acc, 8, 16);
    if (j==0) diag2[n*16 + m] = acc * (w2 * (1.0f/15.0f));
  }
}

// ---- stage one 64-col fp8 B step-tile (16 KiB) via async global->LDS DMA ----
__device__ __forceinline__ void stage_b(const i32x4* __restrict__ centk16,
                                        i32x4* lds, int col0,
                                        int wave, int lane){
  #pragma unroll
  for (int i=0;i<4;i++){
    const int st = i*4 + wave;
    const i32x4* g = centk16 + (size_t)st*NS + col0 + lane;
    __builtin_amdgcn_global_load_lds(
        (const __attribute__((address_space(1))) void*)g,
        (__attribute__((address_space(3))) void*)(lds + (size_t)st*64),
        16, 0, 0);
  }
}

// MX-scaled fp8 MFMA, K=64, identity E8M0 scales (0x7F -> 2^0)
#define MFMAS(a,b,c) __builtin_amdgcn_mfma_scale_f32_32x32x64_f8f6f4( \
    a, b, c, 0, 0, 0, 0x7f7f7f7fu, 0, 0x7f7f7f7fu)

// ---- main: fp8 A in regs (2 rows/lane), 64-col steps, rows share B reads ----
template<bool FROMF32>
__launch_bounds__(256,3)
__global__ void ge2e_main(const float* __restrict__ embf,
                          const unsigned char* __restrict__ embk8,
                          const i32x4* __restrict__ centk16,
                          const float* __restrict__ diag2,
                          float2* __restrict__ msbuf){
  __shared__ i32x4 Bbuf[2][1024];   // 2 x 16 KiB

  const int tid  = threadIdx.x;
  const int lane = tid & 63;
  const int wave = tid >> 6;
  const int l31  = lane & 31, hi = lane >> 5;
  const int strip  = blockIdx.x & 7;
  const int rowBlk = blockIdx.x >> 3;
  const int c0 = strip * SC;
  const int rowA = rowBlk*BMROWS + wave*32 + l31;   // rows rowA and rowA+128
  const int rowB = rowA + 128;

  stage_b(centk16, &Bbuf[0][0], c0, wave, lane);    // step 0

  // A fragments: chunk c covers k = c*64 + hi*32 + (0..31) = st {4c+2hi, +1}
  i32x8 af0[4], af1[4];
  if constexpr (FROMF32){
    #pragma unroll
    for (int c=0;c<4;c++){
      i32x8 o0, o1;
      #pragma unroll
      for (int h=0;h<2;h++){
        const float* q0 = embf + (size_t)rowA*DD + (4*c + 2*hi + h)*16;
        const float* q1 = embf + (size_t)rowB*DD + (4*c + 2*hi + h)*16;
        #pragma unroll
        for (int j=0;j<4;j++){
          o0[h*4+j] = pk4(q0[j*4], q0[j*4+1], q0[j*4+2], q0[j*4+3]);
          o1[h*4+j] = pk4(q1[j*4], q1[j*4+1], q1[j*4+2], q1[j*4+3]);
        }
      }
      af0[c]=o0; af1[c]=o1;
    }
  } else {
    #pragma unroll
    for (int c=0;c<4;c++){
      i32x4 x0 = *(const i32x4*)(embk8 + ((size_t)(4*c+2*hi  )*NMROWS + rowA)*16);
      i32x4 y0 = *(const i32x4*)(embk8 + ((size_t)(4*c+2*hi+1)*NMROWS + rowA)*16);
      i32x4 x1 = *(const i32x4*)(embk8 + ((size_t)(4*c+2*hi  )*NMROWS + rowB)*16);
      i32x4 y1 = *(const i32x4*)(embk8 + ((size_t)(4*c+2*hi+1)*NMROWS + rowB)*16);
      i32x8 o0; o0[0]=x0[0];o0[1]=x0[1];o0[2]=x0[2];o0[3]=x0[3];
                o0[4]=y0[0];o0[5]=y0[1];o0[6]=y0[2];o0[7]=y0[3];
      i32x8 o1; o1[0]=x1[0];o1[1]=x1[1];o1[2]=x1[2];o1[3]=x1[3];
                o1[4]=y1[0];o1[5]=y1[1];o1[6]=y1[2];o1[7]=y1[3];
      af0[c]=o0; af1[c]=o1;
    }
  }

  const float dv0 = diag2[rowA], dv1 = diag2[rowB];
  const int   lab0 = rowA >> 4, lab1 = rowB >> 4;
  const int   labc0 = rowBlk*16;                     // 16 label-cols of block
  const bool  hasdiag = (labc0 >= c0) && (labc0 < c0 + SC);
  const int   dstep = (labc0 - c0) >> 6;             // valid only if hasdiag
  const int   dcg   = ((labc0 - c0) >> 5) & 1;       // 16-col span fits one cg

  f32x16 zz;                       // shared zero C-init (16 regs, hoisted)
  #pragma unroll
  for (int i=0;i<16;i++) zz[i] = 0.f;

  float m0 = -3.0e38f, s0 = 0.f, m1 = -3.0e38f, s1 = 0.f;

  __syncthreads();   // step-0 staging (all waves) drained

  for (int step=0; step<NSTEP; ++step){
    const int cb_ = step & 1;
    if (step+1 < NSTEP)
      stage_b(centk16, &Bbuf[cb_^1][0], c0 + (step+1)*64, wave, lane);

    const i32x4* cur = &Bbuf[cb_][0];

    #pragma unroll
    for (int cg=0; cg<2; ++cg){
      f32x16 accA, accB;
      {
        i32x4 x = cur[(2*hi  )*64 + cg*32 + l31];
        i32x4 y = cur[(2*hi+1)*64 + cg*32 + l31];
        i32x8 bb; bb[0]=x[0];bb[1]=x[1];bb[2]=x[2];bb[3]=x[3];
                  bb[4]=y[0];bb[5]=y[1];bb[6]=y[2];bb[7]=y[3];
        accA = MFMAS(bb, af0[0], zz);      // rows share the B fragment
        accB = MFMAS(bb, af1[0], zz);
      }
      #pragma unroll
      for (int c=1;c<4;c++){
        i32x4 x = cur[(4*c+2*hi  )*64 + cg*32 + l31];
        i32x4 y = cur[(4*c+2*hi+1)*64 + cg*32 + l31];
        i32x8 bb; bb[0]=x[0];bb[1]=x[1];bb[2]=x[2];bb[3]=x[3];
                  bb[4]=y[0];bb[5]=y[1];bb[6]=y[2];bb[7]=y[3];
        accA = MFMAS(bb, af0[c], accA);
        accB = MFMAS(bb, af1[c], accB);
      }

      if (hasdiag && step == dstep && cg == dcg){   // block-uniform, once
        int colbase = c0 + step*64 + cg*32 + 4*hi;
        #pragma unroll
        for (int r=0;r<16;r++){
          int col = colbase + (r&3) + 8*(r>>2);
          if (col == lab0) accA[r] = dv0;   // exact-fp32 self terms
          if (col == lab1) accB[r] = dv1;
        }
      }

      // online softmax (log2 domain), lane-local, defer-max (THR=8)
      float tmA = max16(accA);
      float tmB = max16(accB);
      if (__any(tmA > m0 + THR)){ float mn = fmaxf(m0,tmA); s0 *= EXP2F(m0-mn); m0 = mn; }
      if (__any(tmB > m1 + THR)){ float mn = fmaxf(m1,tmB); s1 *= EXP2F(m1-mn); m1 = mn; }
      float a0 = EXP2F(accA[0]-m0)+EXP2F(accA[1]-m0)+EXP2F(accA[2]-m0)+EXP2F(accA[3]-m0);
      float a1 = EXP2F(accA[4]-m0)+EXP2F(accA[5]-m0)+EXP2F(accA[6]-m0)+EXP2F(accA[7]-m0);
      float a2 = EXP2F(accA[8]-m0)+EXP2F(accA[9]-m0)+EXP2F(accA[10]-m0)+EXP2F(accA[11]-m0);
      float a3 = EXP2F(accA[12]-m0)+EXP2F(accA[13]-m0)+EXP2F(accA[14]-m0)+EXP2F(accA[15]-m0);
      s0 += (a0+a1)+(a2+a3);
      float b0 = EXP2F(accB[0]-m1)+EXP2F(accB[1]-m1)+EXP2F(accB[2]-m1)+EXP2F(accB[3]-m1);
      float b1 = EXP2F(accB[4]-m1)+EXP2F(accB[5]-m1)+EXP2F(accB[6]-m1)+EXP2F(accB[7]-m1);
      float b2 = EXP2F(accB[8]-m1)+EXP2F(accB[9]-m1)+EXP2F(accB[10]-m1)+EXP2F(accB[11]-m1);
      float b3 = EXP2F(accB[12]-m1)+EXP2F(accB[13]-m1)+EXP2F(accB[14]-m1)+EXP2F(accB[15]-m1);
      s1 += (b0+b1)+(b2+b3);
    }

    asm volatile("s_waitcnt vmcnt(0)" ::: "memory");  // own prefetch landed
    __builtin_amdgcn_s_barrier();                     // all reads of cur done
  }

  // merge hi-halves (same row, disjoint col subsets)
  {
    float mo = __shfl_xor(m0,32,64), so = __shfl_xor(s0,32,64);
    float mm = fmaxf(m0,mo);
    float ss = s0*EXP2F(m0-mm) + so*EXP2F(mo-mm);
    if (hi==0) msbuf[(size_t)strip*NMROWS + rowA] = make_float2(mm, ss);
  }
  {
    float mo = __shfl_xor(m1,32,64), so = __shfl_xor(s1,32,64);
    float mm = fmaxf(m1,mo);
    float ss = s1*EXP2F(m1-mm) + so*EXP2F(mo-mm);
    if (hi==0) msbuf[(size_t)strip*NMROWS + rowB] = make_float2(mm, ss);
  }
}

// ---- merge 8 strips per row -> per-row loss term -> per-block partial ----
__launch_bounds__(512)
__global__ void merge_kernel(const float2* __restrict__ msbuf,
                             const float* __restrict__ diag2,
                             float* __restrict__ partials){
  __shared__ float sh[8];
  const int row = blockIdx.x*512 + threadIdx.x;
  float2 p[STRIPS];
  #pragma unroll
  for (int k=0;k<STRIPS;k++) p[k] = msbuf[(size_t)k*NMROWS + row];
  float mm = p[0].x;
  #pragma unroll
  for (int k=1;k<STRIPS;k++) mm = fmaxf(mm, p[k].x);
  float ss = 0.f;
  #pragma unroll
  for (int k=0;k<STRIPS;k++) ss += p[k].y * EXP2F(p[k].x - mm);
  float term = LN2*(mm + LOG2F(ss) - diag2[row]);
  #pragma unroll
  for (int off=32; off; off>>=1) term += __shfl_xor(term, off, 64);
  if ((threadIdx.x & 63)==0) sh[threadIdx.x>>6] = term;
  __syncthreads();
  if (threadIdx.x==0){
    float v = 0.f;
    #pragma unroll
    for (int i=0;i<8;i++) v += sh[i];
    partials[blockIdx.x] = v;
  }
}

__global__ void final_kernel(const float* __restrict__ partials,
                             float* __restrict__ out){
  int tid = threadIdx.x;              // 64
  float v = partials[tid];
  #pragma unroll
  for (int off=32; off; off>>=1) v += __shfl_xor(v, off, 64);
  if (tid==0) out[0] = v * (1.0f/NMROWS);
}

extern "C" void kernel_launch(void* const* d_in, const int* in_sizes, int n_in,
                              void* d_out, int out_size, void* d_ws, size_t ws_size,
                              hipStream_t stream){
  const float* emb = (const float*)d_in[0];
  const float* wp  = (const float*)d_in[1];
  // d_in[2] (b) cancels in the loss; unused.
  float* out = (float*)d_out;
  char* ws = (char*)d_ws;

  const size_t centk_b = (size_t)NS*DD;            // 512 KiB (fp8)
  const size_t embk_b  = (size_t)NMROWS*DD;        // 8 MiB  (fp8)
  const size_t diag_b  = (size_t)NMROWS*4;         // 128 KiB
  const size_t ms_b    = (size_t)STRIPS*NMROWS*8;  // 2 MiB
  const bool useEmbk = ws_size >= centk_b + embk_b + diag_b + ms_b + 1024;

  i32x4* centk16 = (i32x4*)ws;
  size_t off = centk_b;
  unsigned char* embk8 = useEmbk ? (unsigned char*)(ws + off) : nullptr;
  if (useEmbk) off += embk_b;
  float*  diag2 = (float*)(ws + off);  off += diag_b;
  float2* msbuf = (float2*)(ws + off); off += ms_b;
  float*  parts = (float*)(ws + off);

  prep_kernel<<<NS, 256, 0, stream>>>(emb, wp, centk16, embk8, diag2);
  if (useEmbk)
    ge2e_main<false><<<(NMROWS/BMROWS)*STRIPS, 256, 0, stream>>>(emb, embk8, centk16, diag2, msbuf);
  else
    ge2e_main<true><<<(NMROWS/BMROWS)*STRIPS, 256, 0, stream>>>(emb, embk8, centk16, diag2, msbuf);
  merge_kernel<<<NMROWS/512, 512, 0, stream>>>(msbuf, diag2, parts);
  final_kernel<<<1, 64, 0, stream>>>(parts, out);
}